// Round 7
// baseline (524.810 us; speedup 1.0000x reference)
//
#include <hip/hip_runtime.h>
#include <math.h>

#define NFEAT 1024
#define NROWS 32768
#define EPS 1e-5f

#define NB 1024                        // 4 blocks/CU x 256 CUs -> all co-resident
#define RPB (NROWS / NB)               // 32 rows per block
#define FG (NFEAT / 4)                 // 256 float4 col-groups per row

typedef float f32x4 __attribute__((ext_vector_type(4)));

// ws layout:
//   [0 .. 15]   two uint barrier counters (zeroed by 16B memset each launch)
//   then mean: FG f32x4, inv: FG f32x4
//   then partial_s: NB*FG f32x4 (4 MB), partial_q: NB*FG f32x4 (4 MB)

__device__ __forceinline__ void dev_barrier(unsigned* cnt, unsigned target)
{
    __syncthreads();
    if (threadIdx.x == 0) {
        __threadfence();   // make this block's prior stores device-visible
        __hip_atomic_fetch_add(cnt, 1u, __ATOMIC_ACQ_REL, __HIP_MEMORY_SCOPE_AGENT);
        while (__hip_atomic_load(cnt, __ATOMIC_ACQUIRE, __HIP_MEMORY_SCOPE_AGENT) < target)
            __builtin_amdgcn_s_sleep(2);
    }
    __syncthreads();
}

__global__ __launch_bounds__(256, 4) void fused_kernel(
    const float* __restrict__ x,
    f32x4* __restrict__ ps, f32x4* __restrict__ pq,
    f32x4* __restrict__ mean, f32x4* __restrict__ inv,
    unsigned* __restrict__ bar,
    float* __restrict__ out)
{
    const int t = threadIdx.x;                 // col-group 0..255
    const size_t base = (size_t)(blockIdx.x * RPB) * FG + t;
    const f32x4* xv = (const f32x4*)x;

    // ---- phase 1: per-block partial sums over own 32 rows ----
    {
        f32x4 s = {0.f, 0.f, 0.f, 0.f};
        f32x4 q = {0.f, 0.f, 0.f, 0.f};
        #pragma unroll
        for (int r = 0; r < RPB; r += 4) {
            f32x4 v0 = xv[base + (size_t)(r + 0) * FG];
            f32x4 v1 = xv[base + (size_t)(r + 1) * FG];
            f32x4 v2 = xv[base + (size_t)(r + 2) * FG];
            f32x4 v3 = xv[base + (size_t)(r + 3) * FG];
            s += (v0 + v1) + (v2 + v3);
            q += (v0 * v0 + v1 * v1) + (v2 * v2 + v3 * v3);
        }
        ps[(size_t)blockIdx.x * FG + t] = s;
        pq[(size_t)blockIdx.x * FG + t] = q;
    }

    dev_barrier(&bar[0], NB);

    // ---- phase 2: blocks 0..255 finalize stats, one col-group each ----
    if (blockIdx.x < FG) {
        const int cgi = blockIdx.x;
        f32x4 s = {0.f, 0.f, 0.f, 0.f};
        f32x4 q = {0.f, 0.f, 0.f, 0.f};
        #pragma unroll
        for (int k = 0; k < NB / 256; ++k) {   // 4 partial-rows per thread
            s += ps[(size_t)(t + 256 * k) * FG + cgi];
            q += pq[(size_t)(t + 256 * k) * FG + cgi];
        }
        __shared__ f32x4 ls[256];
        __shared__ f32x4 lq[256];
        ls[t] = s; lq[t] = q;
        __syncthreads();
        #pragma unroll
        for (int off = 128; off > 0; off >>= 1) {
            if (t < off) { ls[t] += ls[t + off]; lq[t] += lq[t + off]; }
            __syncthreads();
        }
        if (t == 0) {
            f32x4 S = ls[0], Q = lq[0];
            const float n   = (float)NROWS;
            const float rn  = 1.0f / n;
            const float rn1 = 1.0f / (n - 1.0f);
            f32x4 m = S * rn, iv;
            iv.x = 1.0f / (sqrtf((Q.x - S.x * S.x * rn) * rn1) + EPS);
            iv.y = 1.0f / (sqrtf((Q.y - S.y * S.y * rn) * rn1) + EPS);
            iv.z = 1.0f / (sqrtf((Q.z - S.z * S.z * rn) * rn1) + EPS);
            iv.w = 1.0f / (sqrtf((Q.w - S.w * S.w * rn) * rn1) + EPS);
            mean[cgi] = m;
            inv[cgi]  = iv;
        }
    }

    dev_barrier(&bar[1], NB);

    // ---- phase 3: normalize own 32 rows (own span partially L2-hot) ----
    {
        const f32x4 m  = mean[t];
        const f32x4 iv = inv[t];
        f32x4* ov = (f32x4*)out;
        #pragma unroll
        for (int r = 0; r < RPB; r += 4) {
            f32x4 v0 = xv[base + (size_t)(r + 0) * FG];
            f32x4 v1 = xv[base + (size_t)(r + 1) * FG];
            f32x4 v2 = xv[base + (size_t)(r + 2) * FG];
            f32x4 v3 = xv[base + (size_t)(r + 3) * FG];
            ov[base + (size_t)(r + 0) * FG] = (v0 - m) * iv;
            ov[base + (size_t)(r + 1) * FG] = (v1 - m) * iv;
            ov[base + (size_t)(r + 2) * FG] = (v2 - m) * iv;
            ov[base + (size_t)(r + 3) * FG] = (v3 - m) * iv;
        }
    }
}

extern "C" void kernel_launch(void* const* d_in, const int* in_sizes, int n_in,
                              void* d_out, int out_size, void* d_ws, size_t ws_size,
                              hipStream_t stream) {
    const float* x = (const float*)d_in[0];
    float* out = (float*)d_out;

    unsigned* bar = (unsigned*)d_ws;                 // [4] uints (16 B)
    f32x4* mean = (f32x4*)((char*)d_ws + 16);        // [256] f32x4
    f32x4* inv  = mean + FG;                         // [256] f32x4
    f32x4* ps   = inv + FG;                          // NB*FG f32x4 (4 MB)
    f32x4* pq   = ps + (size_t)NB * FG;              // NB*FG f32x4 (4 MB)

    hipMemsetAsync(d_ws, 0, 16, stream);             // zero barrier counters

    void* kargs[] = { (void*)&x, (void*)&ps, (void*)&pq,
                      (void*)&mean, (void*)&inv, (void*)&bar, (void*)&out };
    hipLaunchKernel((const void*)fused_kernel, dim3(NB), dim3(256),
                    kargs, 0, stream);
}